// Round 5
// baseline (297.610 us; speedup 1.0000x reference)
//
#include <hip/hip_runtime.h>

#define NB 10

typedef float f32x4 __attribute__((ext_vector_type(4)));

// Volatile asm load: cannot be sunk next to its use by the scheduler, so the
// issued loads genuinely stay in flight.
__device__ __forceinline__ f32x4 async_load(const float* p) {
    f32x4 r;
    asm volatile("global_load_dwordx4 %0, %1, off"
                 : "=v"(r)
                 : "v"(p)
                 : "memory");
    return r;
}

__device__ __forceinline__ void accum_pair(const f32x4 c, const f32x4 k,
                                           float acc[NB]) {
#pragma unroll
    for (int e = 0; e < 4; ++e) {
        const int idx = (int)(c[e] * (float)NB);  // conf >= 0: trunc == floor
        const float d = c[e] - k[e];
#pragma unroll
        for (int j = 0; j < NB; ++j)
            acc[j] += (idx == j) ? d : 0.0f;  // idx>=10 (overflow bin) dropped
    }
}

// Fused: per-block bin sums -> plain stores to partials; last-finished block
// (device-scope counter) reduces all partials and writes the final ECE.
// Saves the stage-2 dispatch + inter-kernel gap (~5 us serialized tail in R4).
__global__ __launch_bounds__(256) void ece_fused_kernel(
    const float* __restrict__ conf, const float* __restrict__ corr,
    float* __restrict__ partials, unsigned int* __restrict__ counter,
    float* __restrict__ out, int n)
{
    float acc[NB];
#pragma unroll
    for (int j = 0; j < NB; ++j) acc[j] = 0.0f;

    const int tid = threadIdx.x;
    const int gid = blockIdx.x * blockDim.x + tid;
    const int stride = gridDim.x * blockDim.x;  // in float4 units
    const int n4 = n >> 2;

    int i = gid;

    for (; i + 3 * stride < n4; i += 4 * stride) {
        const float* cb = conf + 4ll * i;
        const float* kb = corr + 4ll * i;
        const long long soff = 4ll * stride;

        f32x4 c0 = async_load(cb);
        f32x4 k0 = async_load(kb);
        f32x4 c1 = async_load(cb + soff);
        f32x4 k1 = async_load(kb + soff);
        f32x4 c2 = async_load(cb + 2 * soff);
        f32x4 k2 = async_load(kb + 2 * soff);
        f32x4 c3 = async_load(cb + 3 * soff);
        f32x4 k3 = async_load(kb + 3 * soff);

        asm volatile("s_waitcnt vmcnt(4)" ::: "memory");
        __builtin_amdgcn_sched_barrier(0);
        accum_pair(c0, k0, acc);
        accum_pair(c1, k1, acc);

        asm volatile("s_waitcnt vmcnt(0)" ::: "memory");
        __builtin_amdgcn_sched_barrier(0);
        accum_pair(c2, k2, acc);
        accum_pair(c3, k3, acc);
    }

    for (; i < n4; i += stride) {
        const f32x4 c = *reinterpret_cast<const f32x4*>(conf + 4ll * i);
        const f32x4 k = *reinterpret_cast<const f32x4*>(corr + 4ll * i);
        accum_pair(c, k, acc);
    }

    if (gid == 0) {
        for (int t = (n4 << 2); t < n; ++t) {
            const float cv = conf[t];
            const int idx = (int)(cv * (float)NB);
            const float d = cv - corr[t];
#pragma unroll
            for (int j = 0; j < NB; ++j)
                acc[j] += (idx == j) ? d : 0.0f;
        }
    }

    // block reduction: [bin][tid] layout -> bank = tid%32, conflict-free
    __shared__ float red[NB][256];
#pragma unroll
    for (int j = 0; j < NB; ++j) red[j][tid] = acc[j];
    __syncthreads();

    for (int s = 128; s > 0; s >>= 1) {
        if (tid < s) {
#pragma unroll
            for (int j = 0; j < NB; ++j) red[j][tid] += red[j][tid + s];
        }
        __syncthreads();
    }

    // bin-major partials so the final reduce reads coalesced
    if (tid < NB) partials[tid * gridDim.x + blockIdx.x] = red[tid][0];

    // release: make this block's partial stores device-visible, then count
    __threadfence();
    __syncthreads();
    __shared__ unsigned int last;
    if (tid == 0) last = atomicAdd(counter, 1u);
    __syncthreads();

    if (last == gridDim.x - 1) {
        // acquire side
        __threadfence();
        float acc2[NB];
#pragma unroll
        for (int j = 0; j < NB; ++j) acc2[j] = 0.0f;
        for (int b = tid; b < (int)gridDim.x; b += 256) {
#pragma unroll
            for (int j = 0; j < NB; ++j)
                acc2[j] += partials[j * gridDim.x + b];
        }
#pragma unroll
        for (int j = 0; j < NB; ++j) red[j][tid] = acc2[j];
        __syncthreads();
        for (int s = 128; s > 0; s >>= 1) {
            if (tid < s) {
#pragma unroll
                for (int j = 0; j < NB; ++j) red[j][tid] += red[j][tid + s];
            }
            __syncthreads();
        }
        if (tid == 0) {
            float s = 0.0f;
#pragma unroll
            for (int j = 0; j < NB; ++j) s += fabsf(red[j][0]);
            out[0] = s / (float)n;
        }
    }
}

extern "C" void kernel_launch(void* const* d_in, const int* in_sizes, int n_in,
                              void* d_out, int out_size, void* d_ws, size_t ws_size,
                              hipStream_t stream) {
    const float* conf = (const float*)d_in[0];
    const float* corr = (const float*)d_in[1];
    float* ws = (float*)d_ws;
    float* out = (float*)d_out;
    const int n = in_sizes[0];

    const int n4 = n >> 2;
    int blocks = (n4 + 255) / 256;
    if (blocks > 2048) blocks = 2048;
    // ws must hold blocks*NB partial floats + 1 counter word
    const int maxblk = (int)((ws_size / sizeof(float) - 1) / NB);
    if (blocks > maxblk) blocks = maxblk;
    if (blocks < 1) blocks = 1;

    float* partials = ws;
    unsigned int* counter = (unsigned int*)(ws + (size_t)blocks * NB);

    hipMemsetAsync(counter, 0, sizeof(unsigned int), stream);
    ece_fused_kernel<<<blocks, 256, 0, stream>>>(conf, corr, partials, counter,
                                                 out, n);
}

// Round 6
// 67.359 us; speedup vs baseline: 4.4182x; 4.4182x over previous
//
#include <hip/hip_runtime.h>

#define NB 10

typedef float f32x4 __attribute__((ext_vector_type(4)));

// Volatile asm load: cannot be sunk next to its use by the scheduler, so the
// issued loads genuinely stay in flight.
__device__ __forceinline__ f32x4 async_load(const float* p) {
    f32x4 r;
    asm volatile("global_load_dwordx4 %0, %1, off"
                 : "=v"(r)
                 : "v"(p)
                 : "memory");
    return r;
}

__device__ __forceinline__ void accum_pair(const f32x4 c, const f32x4 k,
                                           float acc[NB]) {
#pragma unroll
    for (int e = 0; e < 4; ++e) {
        const int idx = (int)(c[e] * (float)NB);  // conf >= 0: trunc == floor
        const float d = c[e] - k[e];
#pragma unroll
        for (int j = 0; j < NB; ++j)
            acc[j] += (idx == j) ? d : 0.0f;  // idx>=10 (overflow bin) dropped
    }
}

// Fused last-block-done reduction WITHOUT __threadfence():
// R5 post-mortem: agent-scope __threadfence() lowers to a full per-XCD L2
// writeback (buffer_wbl2) since XCD L2s are non-coherent -> 2048 blocks x
// ~0.16us = ~330us of cache maintenance. Instead, make only the 16 touched
// lines coherent: RELAXED agent-scope atomic stores (sc-annotated, L2-bypass)
// for the partials, s_waitcnt vmcnt(0) to drain them to the coherence point,
// RELAXED agent-scope counter add, RELAXED agent-scope loads on the reader.
// No wbl2/inv instructions anywhere.
__global__ __launch_bounds__(256) void ece_fused_kernel(
    const float* __restrict__ conf, const float* __restrict__ corr,
    float* __restrict__ partials, unsigned int* __restrict__ counter,
    float* __restrict__ out, int n)
{
    float acc[NB];
#pragma unroll
    for (int j = 0; j < NB; ++j) acc[j] = 0.0f;

    const int tid = threadIdx.x;
    const int gid = blockIdx.x * blockDim.x + tid;
    const int stride = gridDim.x * blockDim.x;  // in float4 units
    const int n4 = n >> 2;

    int i = gid;

    for (; i + 3 * stride < n4; i += 4 * stride) {
        const float* cb = conf + 4ll * i;
        const float* kb = corr + 4ll * i;
        const long long soff = 4ll * stride;

        f32x4 c0 = async_load(cb);
        f32x4 k0 = async_load(kb);
        f32x4 c1 = async_load(cb + soff);
        f32x4 k1 = async_load(kb + soff);
        f32x4 c2 = async_load(cb + 2 * soff);
        f32x4 k2 = async_load(kb + 2 * soff);
        f32x4 c3 = async_load(cb + 3 * soff);
        f32x4 k3 = async_load(kb + 3 * soff);

        asm volatile("s_waitcnt vmcnt(4)" ::: "memory");
        __builtin_amdgcn_sched_barrier(0);
        accum_pair(c0, k0, acc);
        accum_pair(c1, k1, acc);

        asm volatile("s_waitcnt vmcnt(0)" ::: "memory");
        __builtin_amdgcn_sched_barrier(0);
        accum_pair(c2, k2, acc);
        accum_pair(c3, k3, acc);
    }

    for (; i < n4; i += stride) {
        const f32x4 c = *reinterpret_cast<const f32x4*>(conf + 4ll * i);
        const f32x4 k = *reinterpret_cast<const f32x4*>(corr + 4ll * i);
        accum_pair(c, k, acc);
    }

    if (gid == 0) {
        for (int t = (n4 << 2); t < n; ++t) {
            const float cv = conf[t];
            const int idx = (int)(cv * (float)NB);
            const float d = cv - corr[t];
#pragma unroll
            for (int j = 0; j < NB; ++j)
                acc[j] += (idx == j) ? d : 0.0f;
        }
    }

    // block reduction: [bin][tid] layout -> bank = tid%32, conflict-free
    __shared__ float red[NB][256];
#pragma unroll
    for (int j = 0; j < NB; ++j) red[j][tid] = acc[j];
    __syncthreads();

    for (int s = 128; s > 0; s >>= 1) {
        if (tid < s) {
#pragma unroll
            for (int j = 0; j < NB; ++j) red[j][tid] += red[j][tid + s];
        }
        __syncthreads();
    }

    // bin-major partials, written coherently (L2-bypass), no cache flush
    if (tid < NB)
        __hip_atomic_store(&partials[tid * gridDim.x + blockIdx.x],
                           red[tid][0], __ATOMIC_RELAXED,
                           __HIP_MEMORY_SCOPE_AGENT);

    // wave 0 issued the stores; drain them to the coherence point before the
    // counter increment (per-wave program order: stores -> waitcnt -> atomic)
    asm volatile("s_waitcnt vmcnt(0)" ::: "memory");
    __syncthreads();

    __shared__ unsigned int last;
    if (tid == 0)
        last = __hip_atomic_fetch_add(counter, 1u, __ATOMIC_RELAXED,
                                      __HIP_MEMORY_SCOPE_AGENT);
    __syncthreads();

    if (last == gridDim.x - 1) {
        // all other blocks' partials reached the coherence point before their
        // increments; read with L2-bypass loads (no buffer_inv needed)
        float acc2[NB];
#pragma unroll
        for (int j = 0; j < NB; ++j) acc2[j] = 0.0f;
        for (int b = tid; b < (int)gridDim.x; b += 256) {
#pragma unroll
            for (int j = 0; j < NB; ++j)
                acc2[j] += __hip_atomic_load(&partials[j * gridDim.x + b],
                                             __ATOMIC_RELAXED,
                                             __HIP_MEMORY_SCOPE_AGENT);
        }
#pragma unroll
        for (int j = 0; j < NB; ++j) red[j][tid] = acc2[j];
        __syncthreads();
        for (int s = 128; s > 0; s >>= 1) {
            if (tid < s) {
#pragma unroll
                for (int j = 0; j < NB; ++j) red[j][tid] += red[j][tid + s];
            }
            __syncthreads();
        }
        if (tid == 0) {
            float s = 0.0f;
#pragma unroll
            for (int j = 0; j < NB; ++j) s += fabsf(red[j][0]);
            out[0] = s / (float)n;
        }
    }
}

extern "C" void kernel_launch(void* const* d_in, const int* in_sizes, int n_in,
                              void* d_out, int out_size, void* d_ws, size_t ws_size,
                              hipStream_t stream) {
    const float* conf = (const float*)d_in[0];
    const float* corr = (const float*)d_in[1];
    float* ws = (float*)d_ws;
    float* out = (float*)d_out;
    const int n = in_sizes[0];

    const int n4 = n >> 2;
    int blocks = (n4 + 255) / 256;
    if (blocks > 2048) blocks = 2048;
    // ws must hold blocks*NB partial floats + 1 counter word
    const int maxblk = (int)((ws_size / sizeof(float) - 1) / NB);
    if (blocks > maxblk) blocks = maxblk;
    if (blocks < 1) blocks = 1;

    float* partials = ws;
    unsigned int* counter = (unsigned int*)(ws + (size_t)blocks * NB);

    hipMemsetAsync(counter, 0, sizeof(unsigned int), stream);
    ece_fused_kernel<<<blocks, 256, 0, stream>>>(conf, corr, partials, counter,
                                                 out, n);
}

// Round 7
// 54.445 us; speedup vs baseline: 5.4663x; 1.2372x over previous
//
#include <hip/hip_runtime.h>

#define NB 10

typedef float f32x4 __attribute__((ext_vector_type(4)));

// Volatile asm load with 'nt' (non-temporal / no-allocate): the stream is
// read-once, so retaining lines in L1/L2 is pure tag+evict pressure on the
// L2 pass-through path. Volatile also stops the scheduler re-serializing the
// in-flight batch (R2 lesson).
__device__ __forceinline__ f32x4 async_load_nt(const float* p) {
    f32x4 r;
    asm volatile("global_load_dwordx4 %0, %1, off nt"
                 : "=v"(r)
                 : "v"(p)
                 : "memory");
    return r;
}

__device__ __forceinline__ void accum_pair(const f32x4 c, const f32x4 k,
                                           float acc[NB]) {
#pragma unroll
    for (int e = 0; e < 4; ++e) {
        const int idx = (int)(c[e] * (float)NB);  // conf >= 0: trunc == floor
        const float d = c[e] - k[e];
#pragma unroll
        for (int j = 0; j < NB; ++j)
            acc[j] += (idx == j) ? d : 0.0f;  // idx>=10 (overflow bin) dropped
    }
}

// Stage 1: per-block bin sums of (conf - correct), plain stores of partials.
// (R5/R6 post-mortem: both fusion variants lose to XCD-coherence costs —
// agent __threadfence lowers to full L2 writeback (+330us), and L2-bypass
// scoped stores/loads + per-block drains cost more (+12us) than the ~6us
// dispatch gap they save. Two kernels is the right structure.)
__global__ __launch_bounds__(256) void ece_partial_kernel(
    const float* __restrict__ conf, const float* __restrict__ corr,
    float* __restrict__ ws, int n)
{
    float acc[NB];
#pragma unroll
    for (int j = 0; j < NB; ++j) acc[j] = 0.0f;

    const int tid = threadIdx.x;
    const int gid = blockIdx.x * blockDim.x + tid;
    const int stride = gridDim.x * blockDim.x;  // in float4 units
    const int n4 = n >> 2;

    int i = gid;

    for (; i + 3 * stride < n4; i += 4 * stride) {
        const float* cb = conf + 4ll * i;
        const float* kb = corr + 4ll * i;
        const long long soff = 4ll * stride;

        f32x4 c0 = async_load_nt(cb);
        f32x4 k0 = async_load_nt(kb);
        f32x4 c1 = async_load_nt(cb + soff);
        f32x4 k1 = async_load_nt(kb + soff);
        f32x4 c2 = async_load_nt(cb + 2 * soff);
        f32x4 k2 = async_load_nt(kb + 2 * soff);
        f32x4 c3 = async_load_nt(cb + 3 * soff);
        f32x4 k3 = async_load_nt(kb + 3 * soff);

        asm volatile("s_waitcnt vmcnt(4)" ::: "memory");
        __builtin_amdgcn_sched_barrier(0);
        accum_pair(c0, k0, acc);
        accum_pair(c1, k1, acc);

        asm volatile("s_waitcnt vmcnt(0)" ::: "memory");
        __builtin_amdgcn_sched_barrier(0);
        accum_pair(c2, k2, acc);
        accum_pair(c3, k3, acc);
    }

    for (; i < n4; i += stride) {
        const f32x4 c = *reinterpret_cast<const f32x4*>(conf + 4ll * i);
        const f32x4 k = *reinterpret_cast<const f32x4*>(corr + 4ll * i);
        accum_pair(c, k, acc);
    }

    if (gid == 0) {
        for (int t = (n4 << 2); t < n; ++t) {
            const float cv = conf[t];
            const int idx = (int)(cv * (float)NB);
            const float d = cv - corr[t];
#pragma unroll
            for (int j = 0; j < NB; ++j)
                acc[j] += (idx == j) ? d : 0.0f;
        }
    }

    // block reduction: [bin][tid] layout -> bank = tid%32, conflict-free
    __shared__ float red[NB][256];
#pragma unroll
    for (int j = 0; j < NB; ++j) red[j][tid] = acc[j];
    __syncthreads();

    for (int s = 128; s > 0; s >>= 1) {
        if (tid < s) {
#pragma unroll
            for (int j = 0; j < NB; ++j) red[j][tid] += red[j][tid + s];
        }
        __syncthreads();
    }

    // bin-major partials so stage 2 reads are coalesced
    if (tid < NB) ws[tid * gridDim.x + blockIdx.x] = red[tid][0];
}

// Stage 2: reduce nblk x NB partials, ece = sum_j |sum_b ws[j][b]| / n
__global__ __launch_bounds__(1024) void ece_final_kernel(
    const float* __restrict__ ws, float* __restrict__ out, int n, int nblk)
{
    const int tid = threadIdx.x;
    float acc[NB];
#pragma unroll
    for (int j = 0; j < NB; ++j) acc[j] = 0.0f;

    for (int i = tid; i < nblk; i += 1024) {
#pragma unroll
        for (int j = 0; j < NB; ++j) acc[j] += ws[j * nblk + i];
    }

    __shared__ float red[NB][1024];
#pragma unroll
    for (int j = 0; j < NB; ++j) red[j][tid] = acc[j];
    __syncthreads();

    for (int s = 512; s > 0; s >>= 1) {
        if (tid < s) {
#pragma unroll
            for (int j = 0; j < NB; ++j) red[j][tid] += red[j][tid + s];
        }
        __syncthreads();
    }

    if (tid == 0) {
        float s = 0.0f;
#pragma unroll
        for (int j = 0; j < NB; ++j) s += fabsf(red[j][0]);
        out[0] = s / (float)n;
    }
}

extern "C" void kernel_launch(void* const* d_in, const int* in_sizes, int n_in,
                              void* d_out, int out_size, void* d_ws, size_t ws_size,
                              hipStream_t stream) {
    const float* conf = (const float*)d_in[0];
    const float* corr = (const float*)d_in[1];
    float* ws = (float*)d_ws;
    float* out = (float*)d_out;
    const int n = in_sizes[0];

    const int n4 = n >> 2;
    int blocks = (n4 + 255) / 256;
    if (blocks > 2048) blocks = 2048;
    // safety: ws must hold blocks*NB floats
    const int maxblk = (int)(ws_size / (NB * sizeof(float)));
    if (blocks > maxblk) blocks = maxblk;
    if (blocks < 1) blocks = 1;

    ece_partial_kernel<<<blocks, 256, 0, stream>>>(conf, corr, ws, n);
    ece_final_kernel<<<1, 1024, 0, stream>>>(ws, out, n, blocks);
}